// Round 6
// baseline (378.638 us; speedup 1.0000x reference)
//
#include <hip/hip_runtime.h>

// TensorProductConv: Z[rows[e]] += msg(X[cols[e]], Y[e], W[e]),  msg is 352 f32.
// Inputs: X (N,128) f32, Y (E,4) f32, W (E,160) f32, rows (E) int32, cols (E) int32
// Output: Z (N, 352) f32.
//
// ATTRIBUTION ROUND: identical to R5 except tpc_gather is launched 3x
// (idempotent: rewrites every Z row with the same values). From dur:
//   g = (dur - 177.5)/2,  build = 177.5 - g.

#define SQRT3_INV 0.57735026918962576451f
#define SQRT2_INV 0.70710678118654752440f
#define SCAN_CHUNK 512

typedef __attribute__((ext_vector_type(4))) float f4;
typedef __attribute__((ext_vector_type(2))) int   i2;

// ---------- CSR build ----------
__global__ void zero_kernel(int* __restrict__ p, int n) {
    int i = blockIdx.x * blockDim.x + threadIdx.x;
    if (i < n) p[i] = 0;
}

__global__ void hist_kernel(const int* __restrict__ rows, int* __restrict__ deg, int nE) {
    int e = blockIdx.x * blockDim.x + threadIdx.x;
    if (e < nE) atomicAdd(&deg[rows[e]], 1);
}

__global__ void scan_phaseA(const int* __restrict__ deg, int* __restrict__ chunkSums, int n) {
    __shared__ int s[SCAN_CHUNK];
    int t = threadIdx.x;
    int i = blockIdx.x * SCAN_CHUNK + t;
    s[t] = (i < n) ? deg[i] : 0;
    __syncthreads();
    for (int st = SCAN_CHUNK / 2; st > 0; st >>= 1) {
        if (t < st) s[t] += s[t + st];
        __syncthreads();
    }
    if (t == 0) chunkSums[blockIdx.x] = s[0];
}

__global__ void scan_phaseB(const int* __restrict__ chunkSums, int* __restrict__ chunkOffs, int nchunks) {
    __shared__ int s[SCAN_CHUNK];
    int t = threadIdx.x;
    int v0 = (t < nchunks) ? chunkSums[t] : 0;
    s[t] = v0;
    __syncthreads();
    for (int st = 1; st < SCAN_CHUNK; st <<= 1) {
        int v = (t >= st) ? s[t - st] : 0;
        __syncthreads();
        s[t] += v;
        __syncthreads();
    }
    if (t < nchunks) chunkOffs[t] = s[t] - v0;
}

__global__ void scan_phaseC(const int* __restrict__ deg, const int* __restrict__ chunkOffs,
                            int* __restrict__ off, int* __restrict__ cur, int n) {
    __shared__ int s[SCAN_CHUNK];
    int t = threadIdx.x;
    int i = blockIdx.x * SCAN_CHUNK + t;
    int d = (i < n) ? deg[i] : 0;
    s[t] = d;
    __syncthreads();
    for (int st = 1; st < SCAN_CHUNK; st <<= 1) {
        int v = (t >= st) ? s[t - st] : 0;
        __syncthreads();
        s[t] += v;
        __syncthreads();
    }
    int excl = s[t] - d + chunkOffs[blockIdx.x];
    if (i < n) { off[i] = excl; cur[i] = excl; }
    if (i == n - 1) off[n] = excl + d;
}

__global__ void scatter_pack_kernel(const int* __restrict__ rows, const int* __restrict__ cols,
                                    const f4* __restrict__ Y4, int* __restrict__ cur,
                                    i2* __restrict__ ec, f4* __restrict__ yb, int nE) {
    int e = blockIdx.x * blockDim.x + threadIdx.x;
    if (e >= nE) return;
    int p = atomicAdd(&cur[rows[e]], 1);
    i2 r; r.x = e; r.y = cols[e];
    ec[p] = r;
    yb[p] = Y4[e];
}

// ---------- main gather: one node per 32-lane half-wave ----------
__global__ __launch_bounds__(256) void tpc_gather(
    const float* __restrict__ X,
    const float* __restrict__ W,
    const i2* __restrict__ ec,
    const f4* __restrict__ yb,
    const int* __restrict__ off,
    float* __restrict__ Z,
    int n_nodes)
{
    int node = blockIdx.x * 8 + (threadIdx.x >> 5);
    if (node >= n_nodes) return;
    int u = threadIdx.x & 31;

    float a1 = 0.f, a2a = 0.f, a2b = 0.f, a2c = 0.f;
    float a3a = 0.f, a3b = 0.f, a3c = 0.f, a4 = 0.f;
    float a5a = 0.f, a5b = 0.f, a5c = 0.f;

    const int beg = off[node];
    const int end = off[node + 1];

#define EDGE_BODY(EC_, Y_)                                                    \
    do {                                                                      \
        const float* We = W + (size_t)(unsigned)(EC_).x * 160;                \
        const float* Xr = X + (size_t)(unsigned)(EC_).y * 128;                \
        const float x0  = Xr[u];                                              \
        const float x1a = Xr[32 + 3 * u + 0];                                 \
        const float x1b = Xr[32 + 3 * u + 1];                                 \
        const float x1c = Xr[32 + 3 * u + 2];                                 \
        const float y0  = (Y_).x;                                             \
        const float y1a = (Y_).y;                                             \
        const float y1b = (Y_).z;                                             \
        const float y1c = (Y_).w;                                             \
        const float w0 = __builtin_nontemporal_load(We + u);                  \
        const float w1 = __builtin_nontemporal_load(We + 32 + u);             \
        const float w2 = __builtin_nontemporal_load(We + 64 + u);             \
        const float w3 = __builtin_nontemporal_load(We + 96 + u);             \
        const float w4 = __builtin_nontemporal_load(We + 128 + u);            \
        a1 += w0 * x0 * y0;                                                   \
        const float w1x0 = w1 * x0;                                           \
        a2a += w1x0 * y1a; a2b += w1x0 * y1b; a2c += w1x0 * y1c;              \
        const float w2y0 = w2 * y0;                                           \
        a3a += w2y0 * x1a; a3b += w2y0 * x1b; a3c += w2y0 * x1c;              \
        const float dot = x1a * y1a + x1b * y1b + x1c * y1c;                  \
        a4 += w3 * dot * SQRT3_INV;                                           \
        const float w4s = w4 * SQRT2_INV;                                     \
        a5a += w4s * (x1b * y1c - x1c * y1b);                                 \
        a5b += w4s * (x1c * y1a - x1a * y1c);                                 \
        a5c += w4s * (x1a * y1b - x1b * y1a);                                 \
    } while (0)

    int i = beg;
    for (; i + 1 < end; i += 2) {
        const i2 ec0 = __builtin_nontemporal_load(ec + i);
        const i2 ec1 = __builtin_nontemporal_load(ec + i + 1);
        const f4 y0v = __builtin_nontemporal_load(yb + i);
        const f4 y1v = __builtin_nontemporal_load(yb + i + 1);
        EDGE_BODY(ec0, y0v);
        EDGE_BODY(ec1, y1v);
    }
    if (i < end) {
        const i2 ec0 = __builtin_nontemporal_load(ec + i);
        const f4 y0v = __builtin_nontemporal_load(yb + i);
        EDGE_BODY(ec0, y0v);
    }
#undef EDGE_BODY

    float* Zr = Z + (size_t)node * 352;
    __builtin_nontemporal_store(a1,  Zr + u);
    __builtin_nontemporal_store(a2a, Zr + 32 + 3 * u + 0);
    __builtin_nontemporal_store(a2b, Zr + 32 + 3 * u + 1);
    __builtin_nontemporal_store(a2c, Zr + 32 + 3 * u + 2);
    __builtin_nontemporal_store(a3a, Zr + 128 + 3 * u + 0);
    __builtin_nontemporal_store(a3b, Zr + 128 + 3 * u + 1);
    __builtin_nontemporal_store(a3c, Zr + 128 + 3 * u + 2);
    __builtin_nontemporal_store(a4,  Zr + 224 + u);
    __builtin_nontemporal_store(a5a, Zr + 256 + 3 * u + 0);
    __builtin_nontemporal_store(a5b, Zr + 256 + 3 * u + 1);
    __builtin_nontemporal_store(a5c, Zr + 256 + 3 * u + 2);
}

// ---------- fallback (atomic version) if workspace is too small ----------
__global__ __launch_bounds__(256) void tpc_edge_kernel(
    const float* __restrict__ X, const float* __restrict__ Y, const float* __restrict__ W,
    const int* __restrict__ rows, const int* __restrict__ cols, float* __restrict__ Z, int n_edges)
{
    int gid = blockIdx.x * blockDim.x + threadIdx.x;
    int e = gid >> 5;
    int u = gid & 31;
    if (e >= n_edges) return;
    const int r = rows[e];
    const int c = cols[e];
    const float* Xr = X + (size_t)c * 128;
    const float x0 = Xr[u];
    const float x1a = Xr[32 + 3 * u], x1b = Xr[33 + 3 * u], x1c = Xr[34 + 3 * u];
    const float* Ye = Y + (size_t)e * 4;
    const float y0 = Ye[0], y1a = Ye[1], y1b = Ye[2], y1c = Ye[3];
    const float* We = W + (size_t)e * 160;
    const float w0 = We[u], w1 = We[32 + u], w2 = We[64 + u], w3 = We[96 + u], w4 = We[128 + u];
    const float p1 = w0 * x0 * y0;
    const float w1x0 = w1 * x0;
    const float w2y0 = w2 * y0;
    const float dot = x1a * y1a + x1b * y1b + x1c * y1c;
    const float w4s = w4 * SQRT2_INV;
    float* Zr = Z + (size_t)r * 352;
    atomicAdd(&Zr[u], p1);
    atomicAdd(&Zr[32 + 3 * u + 0], w1x0 * y1a);
    atomicAdd(&Zr[32 + 3 * u + 1], w1x0 * y1b);
    atomicAdd(&Zr[32 + 3 * u + 2], w1x0 * y1c);
    atomicAdd(&Zr[128 + 3 * u + 0], w2y0 * x1a);
    atomicAdd(&Zr[128 + 3 * u + 1], w2y0 * x1b);
    atomicAdd(&Zr[128 + 3 * u + 2], w2y0 * x1c);
    atomicAdd(&Zr[224 + u], w3 * dot * SQRT3_INV);
    atomicAdd(&Zr[256 + 3 * u + 0], w4s * (x1b * y1c - x1c * y1b));
    atomicAdd(&Zr[256 + 3 * u + 1], w4s * (x1c * y1a - x1a * y1c));
    atomicAdd(&Zr[256 + 3 * u + 2], w4s * (x1a * y1b - x1b * y1a));
}

extern "C" void kernel_launch(void* const* d_in, const int* in_sizes, int n_in,
                              void* d_out, int out_size, void* d_ws, size_t ws_size,
                              hipStream_t stream) {
    const float* X    = (const float*)d_in[0];
    const float* Y    = (const float*)d_in[1];
    const float* W    = (const float*)d_in[2];
    const int*   rows = (const int*)d_in[3];
    const int*   cols = (const int*)d_in[4];
    float* Z = (float*)d_out;

    const int n_edges = in_sizes[3];
    const int n_nodes = in_sizes[0] / 128;
    const int nchunks = (n_nodes + SCAN_CHUNK - 1) / SCAN_CHUNK;

    size_t need = (size_t)n_edges * 24 +
                  (size_t)(3 * n_nodes + 1 + 2 * nchunks) * sizeof(int);
    if (ws_size < need || nchunks > SCAN_CHUNK) {
        hipMemsetAsync(d_out, 0, (size_t)out_size * sizeof(float), stream);
        const long long threads_total = (long long)n_edges * 32;
        const int grid = (int)((threads_total + 255) / 256);
        tpc_edge_kernel<<<grid, 256, 0, stream>>>(X, Y, W, rows, cols, Z, n_edges);
        return;
    }

    char* base = (char*)d_ws;
    f4* yb = (f4*)base;
    i2* ec = (i2*)(base + (size_t)n_edges * 16);
    int* p  = (int*)(base + (size_t)n_edges * 24);
    int* off       = p;                 p += n_nodes + 1;
    int* cur       = p;                 p += n_nodes;
    int* deg       = p;                 p += n_nodes;
    int* chunkSums = p;                 p += nchunks;
    int* chunkOffs = p;

    const int gE = (n_edges + 255) / 256;
    const int gN = (n_nodes + 255) / 256;

    zero_kernel<<<gN, 256, 0, stream>>>(deg, n_nodes);
    hist_kernel<<<gE, 256, 0, stream>>>(rows, deg, n_edges);
    scan_phaseA<<<nchunks, SCAN_CHUNK, 0, stream>>>(deg, chunkSums, n_nodes);
    scan_phaseB<<<1, SCAN_CHUNK, 0, stream>>>(chunkSums, chunkOffs, nchunks);
    scan_phaseC<<<nchunks, SCAN_CHUNK, 0, stream>>>(deg, chunkOffs, off, cur, n_nodes);
    scatter_pack_kernel<<<gE, 256, 0, stream>>>(rows, cols, (const f4*)Y, cur, ec, yb, n_edges);

    // ATTRIBUTION: launch the (idempotent) gather 3x. dur = build + 3*g.
    const int gG = (n_nodes + 7) / 8;
    tpc_gather<<<gG, 256, 0, stream>>>(X, W, ec, yb, off, Z, n_nodes);
    tpc_gather<<<gG, 256, 0, stream>>>(X, W, ec, yb, off, Z, n_nodes);
    tpc_gather<<<gG, 256, 0, stream>>>(X, W, ec, yb, off, Z, n_nodes);
}

// Round 7
// 142.587 us; speedup vs baseline: 2.6555x; 2.6555x over previous
//
#include <hip/hip_runtime.h>

// TensorProductConv: Z[rows[e]] += msg(X[cols[e]], Y[e], W[e]),  msg is 352 f32.
// Inputs: X (N,128) f32, Y (E,4) f32, W (E,160) f32, rows (E) int32, cols (E) int32
// Output: Z (N, 352) f32.
//
// Build: fixed-capacity binning (K=128 slots/node) — memset(cnt) + one
// scatter_bin kernel. Overflow edges (never in practice) go to a list and are
// atomically added to Z by a cleanup pass after the gather.
// Gather: one 32-lane half-wave per node, accumulate in registers, write Z once.

#define SQRT3_INV 0.57735026918962576451f
#define SQRT2_INV 0.70710678118654752440f
#define KCAP 128

typedef __attribute__((ext_vector_type(2))) int i2;

// ---------- build: bin edges by destination row ----------
__global__ void scatter_bin_kernel(const int* __restrict__ rows, const int* __restrict__ cols,
                                   int* __restrict__ cnt, i2* __restrict__ slots,
                                   int* __restrict__ ovf_cnt, int* __restrict__ ovf_list,
                                   int nE) {
    int e = blockIdx.x * blockDim.x + threadIdx.x;
    if (e >= nE) return;
    int r = rows[e];
    int p = atomicAdd(&cnt[r], 1);
    if (p < KCAP) {
        i2 rec; rec.x = e; rec.y = cols[e];
        slots[(size_t)r * KCAP + p] = rec;
    } else {
        int q = atomicAdd(ovf_cnt, 1);
        ovf_list[q] = e;
    }
}

// ---------- main gather: one node per 32-lane half-wave ----------
__global__ __launch_bounds__(256) void tpc_gather(
    const float* __restrict__ X,
    const float* __restrict__ Y,
    const float* __restrict__ W,
    const i2* __restrict__ slots,
    const int* __restrict__ cnt,
    float* __restrict__ Z,
    int n_nodes)
{
    int node = blockIdx.x * 8 + (threadIdx.x >> 5);   // 8 half-waves per 256-thr block
    if (node >= n_nodes) return;
    int u = threadIdx.x & 31;

    float a1 = 0.f, a2a = 0.f, a2b = 0.f, a2c = 0.f;
    float a3a = 0.f, a3b = 0.f, a3c = 0.f, a4 = 0.f;
    float a5a = 0.f, a5b = 0.f, a5c = 0.f;

    int n = cnt[node];
    if (n > KCAP) n = KCAP;
    const i2* sb = slots + (size_t)node * KCAP;

#define EDGE_BODY(EC_)                                                        \
    do {                                                                      \
        const float* We = W + (size_t)(unsigned)(EC_).x * 160;                \
        const float* Xr = X + (size_t)(unsigned)(EC_).y * 128;                \
        const float* Ye = Y + (size_t)(unsigned)(EC_).x * 4;                  \
        const float x0  = Xr[u];                                              \
        const float x1a = Xr[32 + 3 * u + 0];                                 \
        const float x1b = Xr[32 + 3 * u + 1];                                 \
        const float x1c = Xr[32 + 3 * u + 2];                                 \
        const float y0  = Ye[0];                                              \
        const float y1a = Ye[1];                                              \
        const float y1b = Ye[2];                                              \
        const float y1c = Ye[3];                                              \
        const float w0 = __builtin_nontemporal_load(We + u);                  \
        const float w1 = __builtin_nontemporal_load(We + 32 + u);             \
        const float w2 = __builtin_nontemporal_load(We + 64 + u);             \
        const float w3 = __builtin_nontemporal_load(We + 96 + u);             \
        const float w4 = __builtin_nontemporal_load(We + 128 + u);            \
        a1 += w0 * x0 * y0;                                                   \
        const float w1x0 = w1 * x0;                                           \
        a2a += w1x0 * y1a; a2b += w1x0 * y1b; a2c += w1x0 * y1c;              \
        const float w2y0 = w2 * y0;                                           \
        a3a += w2y0 * x1a; a3b += w2y0 * x1b; a3c += w2y0 * x1c;              \
        const float dot = x1a * y1a + x1b * y1b + x1c * y1c;                  \
        a4 += w3 * dot * SQRT3_INV;                                           \
        const float w4s = w4 * SQRT2_INV;                                     \
        a5a += w4s * (x1b * y1c - x1c * y1b);                                 \
        a5b += w4s * (x1c * y1a - x1a * y1c);                                 \
        a5c += w4s * (x1a * y1b - x1b * y1a);                                 \
    } while (0)

    int i = 0;
    for (; i + 1 < n; i += 2) {
        const i2 ec0 = sb[i];
        const i2 ec1 = sb[i + 1];
        EDGE_BODY(ec0);
        EDGE_BODY(ec1);
    }
    if (i < n) {
        const i2 ec0 = sb[i];
        EDGE_BODY(ec0);
    }
#undef EDGE_BODY

    float* Zr = Z + (size_t)node * 352;
    __builtin_nontemporal_store(a1,  Zr + u);
    __builtin_nontemporal_store(a2a, Zr + 32 + 3 * u + 0);
    __builtin_nontemporal_store(a2b, Zr + 32 + 3 * u + 1);
    __builtin_nontemporal_store(a2c, Zr + 32 + 3 * u + 2);
    __builtin_nontemporal_store(a3a, Zr + 128 + 3 * u + 0);
    __builtin_nontemporal_store(a3b, Zr + 128 + 3 * u + 1);
    __builtin_nontemporal_store(a3c, Zr + 128 + 3 * u + 2);
    __builtin_nontemporal_store(a4,  Zr + 224 + u);
    __builtin_nontemporal_store(a5a, Zr + 256 + 3 * u + 0);
    __builtin_nontemporal_store(a5b, Zr + 256 + 3 * u + 1);
    __builtin_nontemporal_store(a5c, Zr + 256 + 3 * u + 2);
}

// ---------- overflow cleanup: atomically add overflowed edges into Z ----------
__global__ void ovf_kernel(const float* __restrict__ X, const float* __restrict__ Y,
                           const float* __restrict__ W, const int* __restrict__ rows,
                           const int* __restrict__ cols, const int* __restrict__ ovf_cnt,
                           const int* __restrict__ ovf_list, float* __restrict__ Z) {
    const int total = ovf_cnt[0] * 32;
    for (int idx = blockIdx.x * blockDim.x + threadIdx.x; idx < total;
         idx += gridDim.x * blockDim.x) {
        const int e = ovf_list[idx >> 5];
        const int u = idx & 31;
        const int r = rows[e];
        const int c = cols[e];
        const float* Xr = X + (size_t)c * 128;
        const float x0 = Xr[u];
        const float x1a = Xr[32 + 3 * u], x1b = Xr[33 + 3 * u], x1c = Xr[34 + 3 * u];
        const float* Ye = Y + (size_t)e * 4;
        const float y0 = Ye[0], y1a = Ye[1], y1b = Ye[2], y1c = Ye[3];
        const float* We = W + (size_t)e * 160;
        const float w0 = We[u], w1 = We[32 + u], w2 = We[64 + u], w3 = We[96 + u], w4 = We[128 + u];
        const float w1x0 = w1 * x0;
        const float w2y0 = w2 * y0;
        const float dot = x1a * y1a + x1b * y1b + x1c * y1c;
        const float w4s = w4 * SQRT2_INV;
        float* Zr = Z + (size_t)r * 352;
        atomicAdd(&Zr[u], w0 * x0 * y0);
        atomicAdd(&Zr[32 + 3 * u + 0], w1x0 * y1a);
        atomicAdd(&Zr[32 + 3 * u + 1], w1x0 * y1b);
        atomicAdd(&Zr[32 + 3 * u + 2], w1x0 * y1c);
        atomicAdd(&Zr[128 + 3 * u + 0], w2y0 * x1a);
        atomicAdd(&Zr[128 + 3 * u + 1], w2y0 * x1b);
        atomicAdd(&Zr[128 + 3 * u + 2], w2y0 * x1c);
        atomicAdd(&Zr[224 + u], w3 * dot * SQRT3_INV);
        atomicAdd(&Zr[256 + 3 * u + 0], w4s * (x1b * y1c - x1c * y1b));
        atomicAdd(&Zr[256 + 3 * u + 1], w4s * (x1c * y1a - x1a * y1c));
        atomicAdd(&Zr[256 + 3 * u + 2], w4s * (x1a * y1b - x1b * y1a));
    }
}

// ---------- fallback (atomic version) if workspace is too small ----------
__global__ __launch_bounds__(256) void tpc_edge_kernel(
    const float* __restrict__ X, const float* __restrict__ Y, const float* __restrict__ W,
    const int* __restrict__ rows, const int* __restrict__ cols, float* __restrict__ Z, int n_edges)
{
    int gid = blockIdx.x * blockDim.x + threadIdx.x;
    int e = gid >> 5;
    int u = gid & 31;
    if (e >= n_edges) return;
    const int r = rows[e];
    const int c = cols[e];
    const float* Xr = X + (size_t)c * 128;
    const float x0 = Xr[u];
    const float x1a = Xr[32 + 3 * u], x1b = Xr[33 + 3 * u], x1c = Xr[34 + 3 * u];
    const float* Ye = Y + (size_t)e * 4;
    const float y0 = Ye[0], y1a = Ye[1], y1b = Ye[2], y1c = Ye[3];
    const float* We = W + (size_t)e * 160;
    const float w0 = We[u], w1 = We[32 + u], w2 = We[64 + u], w3 = We[96 + u], w4 = We[128 + u];
    const float w1x0 = w1 * x0;
    const float w2y0 = w2 * y0;
    const float dot = x1a * y1a + x1b * y1b + x1c * y1c;
    const float w4s = w4 * SQRT2_INV;
    float* Zr = Z + (size_t)r * 352;
    atomicAdd(&Zr[u], w0 * x0 * y0);
    atomicAdd(&Zr[32 + 3 * u + 0], w1x0 * y1a);
    atomicAdd(&Zr[32 + 3 * u + 1], w1x0 * y1b);
    atomicAdd(&Zr[32 + 3 * u + 2], w1x0 * y1c);
    atomicAdd(&Zr[128 + 3 * u + 0], w2y0 * x1a);
    atomicAdd(&Zr[128 + 3 * u + 1], w2y0 * x1b);
    atomicAdd(&Zr[128 + 3 * u + 2], w2y0 * x1c);
    atomicAdd(&Zr[224 + u], w3 * dot * SQRT3_INV);
    atomicAdd(&Zr[256 + 3 * u + 0], w4s * (x1b * y1c - x1c * y1b));
    atomicAdd(&Zr[256 + 3 * u + 1], w4s * (x1c * y1a - x1a * y1c));
    atomicAdd(&Zr[256 + 3 * u + 2], w4s * (x1a * y1b - x1b * y1a));
}

extern "C" void kernel_launch(void* const* d_in, const int* in_sizes, int n_in,
                              void* d_out, int out_size, void* d_ws, size_t ws_size,
                              hipStream_t stream) {
    const float* X    = (const float*)d_in[0];
    const float* Y    = (const float*)d_in[1];
    const float* W    = (const float*)d_in[2];
    const int*   rows = (const int*)d_in[3];
    const int*   cols = (const int*)d_in[4];
    float* Z = (float*)d_out;

    const int n_edges = in_sizes[3];
    const int n_nodes = in_sizes[0] / 128;

    // ws layout: slots i2[n_nodes*KCAP] | cnt[n_nodes] | ovf_cnt[1] | ovf_list[n_edges]
    size_t slots_bytes = (size_t)n_nodes * KCAP * sizeof(i2);
    size_t need = slots_bytes + (size_t)(n_nodes + 1 + n_edges) * sizeof(int);
    if (ws_size < need) {
        hipMemsetAsync(d_out, 0, (size_t)out_size * sizeof(float), stream);
        const long long threads_total = (long long)n_edges * 32;
        const int grid = (int)((threads_total + 255) / 256);
        tpc_edge_kernel<<<grid, 256, 0, stream>>>(X, Y, W, rows, cols, Z, n_edges);
        return;
    }

    char* base = (char*)d_ws;
    i2*  slots   = (i2*)base;
    int* cnt     = (int*)(base + slots_bytes);
    int* ovf_cnt = cnt + n_nodes;
    int* ovf_list= ovf_cnt + 1;

    // zero cnt + ovf_cnt in one memset
    hipMemsetAsync(cnt, 0, (size_t)(n_nodes + 1) * sizeof(int), stream);

    const int gE = (n_edges + 255) / 256;
    scatter_bin_kernel<<<gE, 256, 0, stream>>>(rows, cols, cnt, slots, ovf_cnt, ovf_list, n_edges);

    const int gG = (n_nodes + 7) / 8;
    tpc_gather<<<gG, 256, 0, stream>>>(X, Y, W, slots, cnt, Z, n_nodes);

    // overflow cleanup (normally zero work)
    ovf_kernel<<<64, 256, 0, stream>>>(X, Y, W, rows, cols, ovf_cnt, ovf_list, Z);
}